// Round 11
// baseline (66.081 us; speedup 1.0000x reference)
//
#include <hip/hip_runtime.h>

#define D 256
#define SCALE 1.69864354f   // sqrt((1/T)*log2e), T=0.5: acc=2.8854*cos -> exp2(acc)=exp(sim/T)
#define EPS 1e-8f

typedef __attribute__((ext_vector_type(8))) __bf16 bf16x8;
typedef __attribute__((ext_vector_type(4))) __bf16 bf16x4;
typedef __attribute__((ext_vector_type(4))) float  f32x4;

// ------ Kernel A: row-normalize [z1;z2] -> bf16 fn (pre-scaled), fused pos --
__global__ __launch_bounds__(256) void normpos_kernel(
    const float* __restrict__ z1, const float* __restrict__ z2,
    __bf16* __restrict__ fn, float* __restrict__ pos, int N) {
  int wid  = threadIdx.x >> 6;
  int lane = threadIdx.x & 63;
  int row  = blockIdx.x * 4 + wid;
  f32x4 a = *(const f32x4*)(z1 + (size_t)row * D + lane * 4);
  f32x4 b = *(const f32x4*)(z2 + (size_t)row * D + lane * 4);
  float s1  = a.x * a.x + a.y * a.y + a.z * a.z + a.w * a.w;
  float s2  = b.x * b.x + b.y * b.y + b.z * b.z + b.w * b.w;
  float dot = a.x * b.x + a.y * b.y + a.z * b.z + a.w * b.w;
  #pragma unroll
  for (int m = 1; m < 64; m <<= 1) {
    s1  += __shfl_xor(s1, m, 64);
    s2  += __shfl_xor(s2, m, 64);
    dot += __shfl_xor(dot, m, 64);
  }
  float inv1 = 1.0f / fmaxf(sqrtf(s1), EPS);
  float inv2 = 1.0f / fmaxf(sqrtf(s2), EPS);
  float q1 = inv1 * SCALE, q2 = inv2 * SCALE;
  bf16x4 o1, o2;
  o1[0] = (__bf16)(a.x * q1); o1[1] = (__bf16)(a.y * q1);
  o1[2] = (__bf16)(a.z * q1); o1[3] = (__bf16)(a.w * q1);
  o2[0] = (__bf16)(b.x * q2); o2[1] = (__bf16)(b.y * q2);
  o2[2] = (__bf16)(b.z * q2); o2[3] = (__bf16)(b.w * q2);
  *(bf16x4*)(fn + (size_t)row * D + lane * 4)       = o1;
  *(bf16x4*)(fn + (size_t)(N + row) * D + lane * 4) = o2;
  if (lane == 0) pos[row] = dot * inv1 * inv2;
}

// -------- Kernel B: denom partials, A-register-resident streaming GEMM -----
// Block = band of 256 rows (4 waves x 64 rows) x chunk of 256 cols (4 tiles
// of 64 cols). A-panel (64 rows x K=256) lives in registers per wave, loaded
// ONCE in MFMA fragment layout. B-tiles (64 cols x 256 k, [col][k] layout)
// double-buffered in LDS via global_load_lds; stage issued AFTER the barrier
// so loads overlap MFMA. 128 MFMA per wave per barrier (4x the old rate).
// Triangle: chunks start at the band's diagonal. Rowsums accumulate in regs
// across the block -> split 32+rb+chunk. Colsums per off-diag tile -> split
// rb. Diag chunk (chunk 0): rowsum only, diag-zero on the t==wid subtile.
// Chunk swizzle: inverse-swizzled GLOBAL source + swizzled ds_read (linear
// LDS dest, rule #21); 2-way bank aliasing only (free, m136).
// mfma_f32_16x16x32_bf16: A row=lane&15, k=(lane>>4)*8+j; B col=lane&15;
// C/D col=lane&15, row=(lane>>4)*4+reg (m89/m91-verified).

__device__ __forceinline__ void stageB(const __bf16* __restrict__ fn,
                                       int colg0, __bf16* lds, int tid) {
  // 64 cols x 256 k = 32 KB = 2048 chunks of 16B; 8 iters x 256 threads.
  #pragma unroll
  for (int it = 0; it < 8; ++it) {
    int s   = it * 256 + tid;     // linear LDS chunk slot (col = s>>5, p = s&31)
    int col = s >> 5;
    int p   = s & 31;
    const __bf16* src =
        fn + (size_t)(colg0 + col) * D + ((p ^ (col & 7)) << 3);
    __builtin_amdgcn_global_load_lds(
        (const __attribute__((address_space(1))) void*)src,
        (__attribute__((address_space(3))) void*)(lds + s * 8), 16, 0, 0);
  }
}

__global__ __launch_bounds__(256, 2) void denom_kernel(
    const __bf16* __restrict__ fn, float* __restrict__ partial, int twoN) {
  __shared__ __bf16 Bs[2][64 * 256];   // 2 x 32 KB
  __shared__ float  redC[2][64][4];    // per-tile col sums by wave

  int tid  = threadIdx.x;
  int wid  = tid >> 6;
  int lane = tid & 63;
  int c = lane & 15;            // A-row / B-col / D-col within 16-tile
  int g = lane >> 4;            // k-group (in) / row-group (out)

  // decode bid -> (rb band, chunk): cum(rb) = rb*(65-rb)/2, 528 blocks
  int bid = blockIdx.x;
  int rb = (int)((65.f - sqrtf(65.f * 65.f - 8.f * (float)bid)) * 0.5f);
  while ((rb + 1) * (65 - (rb + 1)) / 2 <= bid) ++rb;
  while (rb * (65 - rb) / 2 > bid) --rb;
  int chunk = bid - rb * (65 - rb) / 2;       // 0 .. (32-rb-1)
  int rowbase = rb * 256 + wid * 64;          // this wave's 64 rows
  int colg0   = rb * 256 + chunk * 256;       // block's first column
  bool diagchunk = (chunk == 0);

  // issue first B-tile stage, then load A fragments (overlap)
  stageB(fn, colg0, Bs[0], tid);

  bf16x8 a[4][8];   // 64 rows x K=256 in fragment layout: 128 VGPR
  #pragma unroll
  for (int mi = 0; mi < 4; ++mi)
    #pragma unroll
    for (int ks = 0; ks < 8; ++ks)
      a[mi][ks] = *(const bf16x8*)(fn + (size_t)(rowbase + mi * 16 + c) * D +
                                   ks * 32 + g * 8);

  float rsum[16];
  #pragma unroll
  for (int ii = 0; ii < 16; ++ii) rsum[ii] = 0.f;

  #pragma unroll
  for (int t = 0; t < 4; ++t) {
    int cur = t & 1;
    __syncthreads();   // tile t staged (vmcnt drained); redC[t-1] complete
    if (t < 3) stageB(fn, colg0 + (t + 1) * 64, Bs[cur ^ 1], tid);
    // flush col sums of tile t-1 (other redC buffer)
    if (!diagchunk && t > 0 && tid < 64) {
      float v = redC[cur ^ 1][tid][0] + redC[cur ^ 1][tid][1] +
                redC[cur ^ 1][tid][2] + redC[cur ^ 1][tid][3];
      partial[(size_t)rb * twoN + colg0 + (t - 1) * 64 + tid] = v;
    }
    // ---- MFMA: 8 k-steps x 16 tiles, A from regs, B from LDS ----
    f32x4 acc[4][4] = {};
    #pragma unroll
    for (int ks = 0; ks < 8; ++ks) {
      bf16x8 b[4];
      #pragma unroll
      for (int ni = 0; ni < 4; ++ni) {
        int col = ni * 16 + c;
        b[ni] = *(const bf16x8*)((const char*)Bs[cur] + col * 512 +
                                 (((ks * 4 + g) ^ (col & 7)) << 4));
      }
      #pragma unroll
      for (int mi = 0; mi < 4; ++mi)
        #pragma unroll
        for (int ni = 0; ni < 4; ++ni)
          acc[mi][ni] = __builtin_amdgcn_mfma_f32_16x16x32_bf16(
              a[mi][ks], b[ni], acc[mi][ni], 0, 0, 0);
    }
    // ---- epilogue: exp2 (scale pre-folded), rowsum (+colsum off-diag) ----
    if (diagchunk) {
      if (t == wid) {
        #pragma unroll
        for (int mi = 0; mi < 4; ++mi)
          #pragma unroll
          for (int ni = 0; ni < 4; ++ni) {
            int colloc = ni * 16 + c;
            #pragma unroll
            for (int r = 0; r < 4; ++r) {
              int rowloc = mi * 16 + g * 4 + r;
              float e = __builtin_amdgcn_exp2f(acc[mi][ni][r]);
              if (rowloc == colloc) e = 0.f;
              rsum[mi * 4 + r] += e;
            }
          }
      } else {
        #pragma unroll
        for (int mi = 0; mi < 4; ++mi)
          #pragma unroll
          for (int ni = 0; ni < 4; ++ni)
            #pragma unroll
            for (int r = 0; r < 4; ++r)
              rsum[mi * 4 + r] += __builtin_amdgcn_exp2f(acc[mi][ni][r]);
      }
    } else {
      float csum[4] = {0.f, 0.f, 0.f, 0.f};
      #pragma unroll
      for (int mi = 0; mi < 4; ++mi)
        #pragma unroll
        for (int ni = 0; ni < 4; ++ni)
          #pragma unroll
          for (int r = 0; r < 4; ++r) {
            float e = __builtin_amdgcn_exp2f(acc[mi][ni][r]);
            rsum[mi * 4 + r] += e;
            csum[ni]         += e;
          }
      // reduce col sums across the 4 row-groups g (lane bits 4-5)
      #pragma unroll
      for (int ni = 0; ni < 4; ++ni) {
        float v = csum[ni];
        v += __shfl_xor(v, 16, 64);
        v += __shfl_xor(v, 32, 64);
        csum[ni] = v;
      }
      if (g == 0) {
        #pragma unroll
        for (int ni = 0; ni < 4; ++ni)
          redC[cur][ni * 16 + c][wid] = csum[ni];
      }
    }
  }
  // final colsum flush (tile 3, redC[1])
  if (!diagchunk) {
    __syncthreads();
    if (tid < 64) {
      float v = redC[1][tid][0] + redC[1][tid][1] +
                redC[1][tid][2] + redC[1][tid][3];
      partial[(size_t)rb * twoN + colg0 + 3 * 64 + tid] = v;
    }
  }
  // rowsum: reduce across the 16 column-lanes once per block, write split
  #pragma unroll
  for (int ii = 0; ii < 16; ++ii) {
    float v = rsum[ii];
    v += __shfl_xor(v, 1, 64);
    v += __shfl_xor(v, 2, 64);
    v += __shfl_xor(v, 4, 64);
    v += __shfl_xor(v, 8, 64);
    rsum[ii] = v;
  }
  if (c == 0) {
    float* dst = partial + (size_t)(32 + rb + chunk) * twoN + rowbase;
    #pragma unroll
    for (int mi = 0; mi < 4; ++mi) {
      f32x4 v;
      v.x = rsum[mi * 4 + 0]; v.y = rsum[mi * 4 + 1];
      v.z = rsum[mi * 4 + 2]; v.w = rsum[mi * 4 + 3];
      *(f32x4*)(dst + mi * 16 + g * 4) = v;
    }
  }
}

// ------- Kernel C1: per-band sums of log(denom), pos (32 valid splits) -----
__global__ __launch_bounds__(256) void reduce1_kernel(
    const float* __restrict__ partial, const float* __restrict__ pos,
    float* __restrict__ bsum, int twoN, int N) {
  int rbi = blockIdx.x;            // block == 256-row band
  int row = rbi * 256 + threadIdx.x;
  int wid = threadIdx.x >> 6, lane = threadIdx.x & 63;
  float denom = 0.f;
  for (int s = 0; s < rbi; ++s)    denom += partial[(size_t)s * twoN + row];
  for (int q = rbi; q < 32; ++q)   denom += partial[(size_t)(32 + q) * twoN + row];
  float ld = logf(denom);
  float p  = (row < N) ? pos[row] : 0.f;
  #pragma unroll
  for (int m = 1; m < 64; m <<= 1) {
    ld += __shfl_xor(ld, m, 64);
    p  += __shfl_xor(p, m, 64);
  }
  __shared__ float sld[4], spo[4];
  if (lane == 0) { sld[wid] = ld; spo[wid] = p; }
  __syncthreads();
  if (threadIdx.x == 0) {
    bsum[blockIdx.x]      = sld[0] + sld[1] + sld[2] + sld[3];
    bsum[32 + blockIdx.x] = spo[0] + spo[1] + spo[2] + spo[3];
  }
}

// ---------------- Kernel C2: final scalar loss -----------------------------
__global__ void reduce2_kernel(const float* __restrict__ bsum,
                               float* __restrict__ out, int twoN, int N,
                               int nblk) {
  int t = threadIdx.x;
  float ld = (t < nblk) ? bsum[t] : 0.f;
  float p  = (t < nblk) ? bsum[32 + t] : 0.f;
  #pragma unroll
  for (int m = 1; m < 64; m <<= 1) {
    ld += __shfl_xor(ld, m, 64);
    p  += __shfl_xor(p, m, 64);
  }
  if (t == 0) out[0] = ld / (float)twoN - 2.f * (p / (float)N);
}

extern "C" void kernel_launch(void* const* d_in, const int* in_sizes, int n_in,
                              void* d_out, int out_size, void* d_ws,
                              size_t ws_size, hipStream_t stream) {
  const float* z1 = (const float*)d_in[0];
  const float* z2 = (const float*)d_in[1];
  int N = in_sizes[0] / D;   // 4096
  int twoN = 2 * N;          // 8192

  // workspace layout
  __bf16* fn      = (__bf16*)d_ws;                               // 4 MB
  float*  partial = (float*)((char*)d_ws + (size_t)twoN * D * 2);// 2 MB (64 splits)
  float*  pos     = (float*)((char*)partial + (size_t)64 * twoN * 4);
  float*  bsum    = (float*)((char*)pos + (size_t)N * 4);        // 64 floats

  normpos_kernel<<<N / 4, 256, 0, stream>>>(z1, z2, fn, pos, N);
  denom_kernel<<<528, 256, 0, stream>>>(fn, partial, twoN);
  reduce1_kernel<<<32, 256, 0, stream>>>(partial, pos, bsum, twoN, N);
  reduce2_kernel<<<1, 64, 0, stream>>>(bsum, (float*)d_out, twoN, N, 32);
}